// Round 12
// baseline (253.468 us; speedup 1.0000x reference)
//
#include <hip/hip_runtime.h>
#include <math.h>

#define NMOL  1024
#define N     128          // atoms per molecule (Schur-reduced SPD system size)
#define NELEM 10
#define BLOCK 256          // 2 molecules per block: waves 0,1 = mol0; waves 2,3 = mol1
#define PW    16           // panel width (was 8): halves phase/barrier count
#define NPAN  8            // 128 / 16
#define PSTR  20           // P row stride (16 data + 4 pad)
#define USTR  132          // U-panel row stride

typedef __attribute__((ext_vector_type(4))) float f4;

// R11 (balanced group ownership, Phase A/B factor) with PW=16: per-panel
// issue is ~3K cyc but each panel costs ~22K -> ~85% is per-phase latency
// (barriers, dependent chains) at the 8-waves/CU occupancy cap. Halving
// panel count (NPAN 8) halves the phase count at identical total FMA work.
// Wave wv owns 16-col groups g with g&1==wv: panel p wholly owned by wave
// p&1 (8-lane in-register 16x16 LU + fused rhs), trailing groups split
// evenly. Geometry arrays overlay P (dead after tile fill) -> 57KB LDS,
// still 2 blocks/CU. launch_bounds w=2 -> 128-VGPR budget, no spill.

__global__ __launch_bounds__(BLOCK, 2) void ceq_solve_kernel(
    const float* __restrict__ eneg,
    const float* __restrict__ positions,
    const float* __restrict__ node_attrs,
    const float* __restrict__ hardness,
    const float* __restrict__ total_charge,
    const int*   __restrict__ atomic_numbers,
    float* __restrict__ out)
{
    __shared__ __align__(16) float P[2][N * PSTR];         // staged panel rows (+geom overlay)
    __shared__ __align__(16) float Up[2][PW * USTR];       // U rows (D*L^T)
    __shared__ __align__(16) float Ublk[2][NPAN][PW][PW];  // 16x16 diag blocks (L\U packed)
    __shared__ float Dinv[2][PW], Dd[2][PW];               // 1/diag, diag of panel
    __shared__ __align__(16) float rhsY[2][N], rhsZ[2][N];
    __shared__ __align__(16) float sxY[2][N], sxZ[2][N];
    __shared__ float lamS[2];

    const int tid  = threadIdx.x;
    const int lane = tid & 63;
    const int g    = tid >> 7;        // molecule within block
    const int gt   = tid & 127;       // thread within molecule
    const int wv   = (tid >> 6) & 1;  // wave within molecule
    const int r0   = 2 * lane;
    const int r1   = r0 + 1;
    const int mol  = 2 * blockIdx.x + g;
    const int base = mol * N;

    // geometry overlay on P (dead once register tiles are built)
    float* px  = &P[g][0 * N];
    float* py  = &P[g][1 * N];
    float* pz  = &P[g][2 * N];
    float* sg  = &P[g][3 * N];
    float* dgv = &P[g][4 * N];

    // ---- per-atom precompute (thread gt loads atom gt of its molecule) ----
    {
        const int i = gt;
        const int Z = atomic_numbers[base + i];
        const float rad = 0.3f + 0.02f * (float)Z;
        sg[i] = rad * rad;
        const float* na = node_attrs + (size_t)(base + i) * NELEM;
        float best = na[0]; int bi = 0;
        #pragma unroll
        for (int e = 1; e < NELEM; ++e) {
            float v = na[e];
            if (v > best) { best = v; bi = e; }     // first-max = jnp.argmax
        }
        dgv[i] = hardness[bi] + 0.5641895835477563f / rad;  // h + 1/(sqrt(pi) r)
        const float* p = positions + (size_t)(base + i) * 3;
        px[i] = p[0]; py[i] = p[1]; pz[i] = p[2];
        rhsY[g][i] = -eneg[base + i];   // A y = b
        rhsZ[g][i] = 1.0f;              // A z = 1
    }
    __syncthreads();

    // ---- fill register tiles: rows r0,r1; f4 c -> cols 32*(c>>2)+16*wv+4*(c&3) ----
    f4 Ar0[16], Ar1[16];
    {
        const float x0 = px[r0], y0 = py[r0], z0 = pz[r0];
        const float s0 = sg[r0], d0 = dgv[r0];
        const float x1 = px[r1], y1 = py[r1], z1 = pz[r1];
        const float s1 = sg[r1], d1 = dgv[r1];
        #pragma unroll
        for (int c = 0; c < 16; ++c) {
            const int jb = 32 * (c >> 2) + 16 * wv + 4 * (c & 3);
            f4 v0, v1;
            #pragma unroll
            for (int e = 0; e < 4; ++e) {
                const int j = jb + e;
                float a0, a1;
                if (j == r0) a0 = d0;
                else {
                    const float dx = x0 - px[j], dy = y0 - py[j], dz = z0 - pz[j];
                    const float d = sqrtf(dx * dx + dy * dy + dz * dz);
                    a0 = erff(d / (1.4142135623730951f * sqrtf(s0 + sg[j]))) / d;
                }
                if (j == r1) a1 = d1;
                else {
                    const float dx = x1 - px[j], dy = y1 - py[j], dz = z1 - pz[j];
                    const float d = sqrtf(dx * dx + dy * dy + dz * dz);
                    a1 = erff(d / (1.4142135623730951f * sqrtf(s1 + sg[j]))) / d;
                }
                ((float*)&v0)[e] = a0;
                ((float*)&v1)[e] = a1;
            }
            Ar0[c] = v0;
            Ar1[c] = v1;
        }
    }
    __syncthreads();   // geom overlay dead; P may now be overwritten

    // ================= blocked LDL^T, A register-resident =================
    for (int p = 0; p < NPAN; ++p) {
        const int k0 = PW * p;
        const int k  = p >> 1;               // owner wave's local group 0..3

        // ---- stage trailing panel rows -> P, + Phase A on the 8 owner lanes ----
        if (wv == (p & 1) && lane >= 8 * p) {
            f4 a0, a1, a2, a3, b0, b1, b2, b3;
            switch (k) {
                case 0:  a0=Ar0[0];  a1=Ar0[1];  a2=Ar0[2];  a3=Ar0[3];
                         b0=Ar1[0];  b1=Ar1[1];  b2=Ar1[2];  b3=Ar1[3];  break;
                case 1:  a0=Ar0[4];  a1=Ar0[5];  a2=Ar0[6];  a3=Ar0[7];
                         b0=Ar1[4];  b1=Ar1[5];  b2=Ar1[6];  b3=Ar1[7];  break;
                case 2:  a0=Ar0[8];  a1=Ar0[9];  a2=Ar0[10]; a3=Ar0[11];
                         b0=Ar1[8];  b1=Ar1[9];  b2=Ar1[10]; b3=Ar1[11]; break;
                default: a0=Ar0[12]; a1=Ar0[13]; a2=Ar0[14]; a3=Ar0[15];
                         b0=Ar1[12]; b1=Ar1[13]; b2=Ar1[14]; b3=Ar1[15]; break;
            }
            if (lane >= 8 * p + 8) {          // rows >= k0+16: stage for phase B
                *(f4*)&P[g][r0 * PSTR + 0] = a0; *(f4*)&P[g][r0 * PSTR + 4]  = a1;
                *(f4*)&P[g][r0 * PSTR + 8] = a2; *(f4*)&P[g][r0 * PSTR + 12] = a3;
                *(f4*)&P[g][r1 * PSTR + 0] = b0; *(f4*)&P[g][r1 * PSTR + 4]  = b1;
                *(f4*)&P[g][r1 * PSTR + 8] = b2; *(f4*)&P[g][r1 * PSTR + 12] = b3;
            } else {                          // Phase A: 8-lane 16x16 LU + fused rhs
                float u0[PW] = { a0.x,a0.y,a0.z,a0.w, a1.x,a1.y,a1.z,a1.w,
                                 a2.x,a2.y,a2.z,a2.w, a3.x,a3.y,a3.z,a3.w };
                float u1[PW] = { b0.x,b0.y,b0.z,b0.w, b1.x,b1.y,b1.z,b1.w,
                                 b2.x,b2.y,b2.z,b2.w, b3.x,b3.y,b3.z,b3.w };
                float ry0 = rhsY[g][r0], rz0 = rhsZ[g][r0];
                float ry1 = rhsY[g][r1], rz1 = rhsZ[g][r1];
                const int rl = lane - 8 * p;  // 0..7: rows 2rl, 2rl+1 of the panel
                #pragma unroll
                for (int kk = 0; kk < PW; ++kk) {
                    const int src = 8 * p + (kk >> 1);
                    float pr[PW];
                    #pragma unroll
                    for (int j = kk; j < PW; ++j)
                        pr[j] = __shfl((kk & 1) ? u1[j] : u0[j], src);
                    const float cY = __shfl((kk & 1) ? ry1 : ry0, src);
                    const float cZ = __shfl((kk & 1) ? rz1 : rz0, src);
                    const float dinv = 1.0f / pr[kk];
                    if (2 * rl > kk) {
                        const float m = u0[kk] * dinv; u0[kk] = m;
                        #pragma unroll
                        for (int j = kk + 1; j < PW; ++j) u0[j] -= m * pr[j];
                        ry0 -= m * cY; rz0 -= m * cZ;
                    }
                    if (2 * rl + 1 > kk) {
                        const float m = u1[kk] * dinv; u1[kk] = m;
                        #pragma unroll
                        for (int j = kk + 1; j < PW; ++j) u1[j] -= m * pr[j];
                        ry1 -= m * cY; rz1 -= m * cZ;
                    }
                    if (rl == (kk >> 1)) { Dinv[g][kk] = dinv; Dd[g][kk] = pr[kk]; }
                }
                f4 w;
                w = (f4){u0[0],u0[1],u0[2],u0[3]};    *(f4*)&Ublk[g][p][2*rl][0]  = w;
                w = (f4){u0[4],u0[5],u0[6],u0[7]};    *(f4*)&Ublk[g][p][2*rl][4]  = w;
                w = (f4){u0[8],u0[9],u0[10],u0[11]};  *(f4*)&Ublk[g][p][2*rl][8]  = w;
                w = (f4){u0[12],u0[13],u0[14],u0[15]};*(f4*)&Ublk[g][p][2*rl][12] = w;
                w = (f4){u1[0],u1[1],u1[2],u1[3]};    *(f4*)&Ublk[g][p][2*rl+1][0]  = w;
                w = (f4){u1[4],u1[5],u1[6],u1[7]};    *(f4*)&Ublk[g][p][2*rl+1][4]  = w;
                w = (f4){u1[8],u1[9],u1[10],u1[11]};  *(f4*)&Ublk[g][p][2*rl+1][8]  = w;
                w = (f4){u1[12],u1[13],u1[14],u1[15]};*(f4*)&Ublk[g][p][2*rl+1][12] = w;
                rhsY[g][r0] = ry0; rhsZ[g][r0] = rz0;
                rhsY[g][r1] = ry1; rhsZ[g][r1] = rz1;
            }
        }
        __syncthreads();

        // ---- Phase B: all 128 threads, one trailing row each ----
        const int nb = (N - PW) - k0;         // 112 - 16p trailing rows
        if (gt < nb) {
            const int i = k0 + PW + gt;
            f4 A0 = *(const f4*)&P[g][i * PSTR + 0], A1 = *(const f4*)&P[g][i * PSTR + 4];
            f4 A2 = *(const f4*)&P[g][i * PSTR + 8], A3 = *(const f4*)&P[g][i * PSTR + 12];
            float av[PW] = { A0.x,A0.y,A0.z,A0.w, A1.x,A1.y,A1.z,A1.w,
                             A2.x,A2.y,A2.z,A2.w, A3.x,A3.y,A3.z,A3.w };
            float m[PW];
            #pragma unroll
            for (int j = 0; j < PW; ++j) {
                float acc = av[j];
                #pragma unroll
                for (int t = 0; t < j; ++t) acc -= m[t] * Ublk[g][p][t][j];
                m[j] = acc * Dinv[g][j];
            }
            f4 w;
            w = (f4){m[0],m[1],m[2],m[3]};     *(f4*)&P[g][i * PSTR + 0]  = w;
            w = (f4){m[4],m[5],m[6],m[7]};     *(f4*)&P[g][i * PSTR + 4]  = w;
            w = (f4){m[8],m[9],m[10],m[11]};   *(f4*)&P[g][i * PSTR + 8]  = w;
            w = (f4){m[12],m[13],m[14],m[15]}; *(f4*)&P[g][i * PSTR + 12] = w;
            #pragma unroll
            for (int u = 0; u < PW; ++u) Up[g][u * USTR + i] = m[u] * Dd[g][u];
            float ry = rhsY[g][i], rz = rhsZ[g][i];
            #pragma unroll
            for (int t = 0; t < PW; ++t) {
                ry -= m[t] * rhsY[g][k0 + t];
                rz -= m[t] * rhsZ[g][k0 + t];
            }
            rhsY[g][i] = ry; rhsZ[g][i] = rz;
        }
        __syncthreads();

        // ---- owner reload + trailing GEMM (groups t > p, parity-split) ----
        if (lane >= 8 * p && lane < 8 * p + 8) {     // rows k0..k0+15: pull U rows back
            const int u0r = r0 - k0, u1r = u0r + 1;
            #pragma unroll
            for (int c = 0; c < 16; ++c) {
                const int t  = 2 * (c >> 2) + wv;
                const int jb = 32 * (c >> 2) + 16 * wv + 4 * (c & 3);
                if (t > p) {
                    Ar0[c] = *(const f4*)&Up[g][u0r * USTR + jb];
                    Ar1[c] = *(const f4*)&Up[g][u1r * USTR + jb];
                }
            }
        }
        const bool hasmat = (6 + wv) > p;             // wave's largest group vs p
        if (hasmat && lane >= 8 * p + 8) {            // rows >= k0+16
            float lA0[PW], lA1[PW];
            {
                f4 a = *(const f4*)&P[g][r0 * PSTR + 0], b = *(const f4*)&P[g][r0 * PSTR + 4];
                f4 c2 = *(const f4*)&P[g][r0 * PSTR + 8], d2 = *(const f4*)&P[g][r0 * PSTR + 12];
                lA0[0]=a.x; lA0[1]=a.y; lA0[2]=a.z; lA0[3]=a.w;
                lA0[4]=b.x; lA0[5]=b.y; lA0[6]=b.z; lA0[7]=b.w;
                lA0[8]=c2.x; lA0[9]=c2.y; lA0[10]=c2.z; lA0[11]=c2.w;
                lA0[12]=d2.x; lA0[13]=d2.y; lA0[14]=d2.z; lA0[15]=d2.w;
                f4 e = *(const f4*)&P[g][r1 * PSTR + 0], f = *(const f4*)&P[g][r1 * PSTR + 4];
                f4 h = *(const f4*)&P[g][r1 * PSTR + 8], i2 = *(const f4*)&P[g][r1 * PSTR + 12];
                lA1[0]=e.x; lA1[1]=e.y; lA1[2]=e.z; lA1[3]=e.w;
                lA1[4]=f.x; lA1[5]=f.y; lA1[6]=f.z; lA1[7]=f.w;
                lA1[8]=h.x; lA1[9]=h.y; lA1[10]=h.z; lA1[11]=h.w;
                lA1[12]=i2.x; lA1[13]=i2.y; lA1[14]=i2.z; lA1[15]=i2.w;
            }
            #pragma unroll
            for (int c = 0; c < 16; ++c) {
                const int t  = 2 * (c >> 2) + wv;
                const int jb = 32 * (c >> 2) + 16 * wv + 4 * (c & 3);
                if (t > p) {
                    f4 acc0 = Ar0[c], acc1 = Ar1[c];
                    #pragma unroll
                    for (int u = 0; u < PW; ++u) {
                        const f4 uv = *(const f4*)&Up[g][u * USTR + jb]; // broadcast
                        acc0 -= uv * lA0[u];
                        acc1 -= uv * lA1[u];
                    }
                    Ar0[c] = acc0; Ar1[c] = acc1;
                }
            }
        }
        __syncthreads();
    }

    // ================= blocked back substitution (both RHS, both mols) =================
    for (int pb = NPAN - 1; pb >= 0; --pb) {
        const int k0 = PW * pb;
        if (tid < 4) {                                // 4 parallel 16x16 upper-tri solves
            const int gg = tid >> 1;
            float* rhs = (tid & 1) ? rhsZ[gg] : rhsY[gg];
            float* sx  = (tid & 1) ? sxZ[gg]  : sxY[gg];
            float x[PW];
            #pragma unroll
            for (int kk = PW - 1; kk >= 0; --kk) {
                float acc = rhs[k0 + kk];
                #pragma unroll
                for (int jj = kk + 1; jj < PW; ++jj) acc -= Ublk[gg][pb][kk][jj] * x[jj];
                x[kk] = acc / Ublk[gg][pb][kk][kk];
                sx[k0 + kk] = x[kk];
            }
        }
        __syncthreads();
        if (wv == (pb & 1) && lane < 8 * pb) {        // rank-16 back-update from regs
            f4 a0, a1, a2, a3, b0, b1, b2, b3;
            switch (pb >> 1) {
                case 0:  a0=Ar0[0];  a1=Ar0[1];  a2=Ar0[2];  a3=Ar0[3];
                         b0=Ar1[0];  b1=Ar1[1];  b2=Ar1[2];  b3=Ar1[3];  break;
                case 1:  a0=Ar0[4];  a1=Ar0[5];  a2=Ar0[6];  a3=Ar0[7];
                         b0=Ar1[4];  b1=Ar1[5];  b2=Ar1[6];  b3=Ar1[7];  break;
                case 2:  a0=Ar0[8];  a1=Ar0[9];  a2=Ar0[10]; a3=Ar0[11];
                         b0=Ar1[8];  b1=Ar1[9];  b2=Ar1[10]; b3=Ar1[11]; break;
                default: a0=Ar0[12]; a1=Ar0[13]; a2=Ar0[14]; a3=Ar0[15];
                         b0=Ar1[12]; b1=Ar1[13]; b2=Ar1[14]; b3=Ar1[15]; break;
            }
            const f4 sy0 = *(const f4*)&sxY[g][k0 + 0],  sy1 = *(const f4*)&sxY[g][k0 + 4];
            const f4 sy2 = *(const f4*)&sxY[g][k0 + 8],  sy3 = *(const f4*)&sxY[g][k0 + 12];
            const f4 sz0 = *(const f4*)&sxZ[g][k0 + 0],  sz1 = *(const f4*)&sxZ[g][k0 + 4];
            const f4 sz2 = *(const f4*)&sxZ[g][k0 + 8],  sz3 = *(const f4*)&sxZ[g][k0 + 12];
            f4 ty0 = a0 * sy0 + a1 * sy1 + a2 * sy2 + a3 * sy3;
            f4 ty1 = b0 * sy0 + b1 * sy1 + b2 * sy2 + b3 * sy3;
            f4 tz0 = a0 * sz0 + a1 * sz1 + a2 * sz2 + a3 * sz3;
            f4 tz1 = b0 * sz0 + b1 * sz1 + b2 * sz2 + b3 * sz3;
            rhsY[g][r0] -= ty0.x + ty0.y + ty0.z + ty0.w;
            rhsY[g][r1] -= ty1.x + ty1.y + ty1.z + ty1.w;
            rhsZ[g][r0] -= tz0.x + tz0.y + tz0.z + tz0.w;
            rhsZ[g][r1] -= tz1.x + tz1.y + tz1.z + tz1.w;
        }
        __syncthreads();
    }

    // ---- Schur closure: lambda = (1'y - Q)/(1'z - 1); q = y - lambda z ----
    if (wv == 0) {
        float vY = sxY[g][lane] + sxY[g][lane + 64];
        float vZ = sxZ[g][lane] + sxZ[g][lane + 64];
        #pragma unroll
        for (int off = 32; off; off >>= 1) {
            vY += __shfl_xor(vY, off);
            vZ += __shfl_xor(vZ, off);
        }
        if (lane == 0) lamS[g] = (vY - total_charge[mol]) / (vZ - 1.0f);
    }
    __syncthreads();
    out[base + gt] = sxY[g][gt] - lamS[g] * sxZ[g][gt];
}

extern "C" void kernel_launch(void* const* d_in, const int* in_sizes, int n_in,
                              void* d_out, int out_size, void* d_ws, size_t ws_size,
                              hipStream_t stream) {
    const float* eneg           = (const float*)d_in[0];
    const float* positions      = (const float*)d_in[1];
    const float* node_attrs     = (const float*)d_in[2];
    const float* hardness       = (const float*)d_in[3];
    const float* total_charge   = (const float*)d_in[4];
    // d_in[5] = batch (unused: equal-sized sorted molecules)
    const int*   atomic_numbers = (const int*)d_in[6];
    float* out = (float*)d_out;

    ceq_solve_kernel<<<NMOL / 2, BLOCK, 0, stream>>>(
        eneg, positions, node_attrs, hardness, total_charge, atomic_numbers, out);
}